// Round 6
// baseline (149.868 us; speedup 1.0000x reference)
//
#include <hip/hip_runtime.h>

// SIRD RK4, round 19: stride-8 handoff — amortize the producer's ds_writes
// to 0.25 slots/tstep.
//
// Machine model (fits R13/R16/R18 within 1%): producer wave is ISSUE-bound
// at ~4.7 cyc/slot (hard lone-wave cadence); chain length does not bind
// (R16 9-op chain == R13 12-op chain in time). Only slot count matters.
// R18 = 23.1 slots/tstep -> 108.8 cyc/tstep (measured 108.75).
//
// Accuracy arithmetic forbids cheaper integrators: RK4 h=1 rel err/step at
// lambda*h=0.5 is 1.0e-4 -> ~28k abs at peak (passes 65536 with ~2.3x
// margin); h=2 -> 3.7e-3/step -> ~480k FAIL; RK3 h=1 -> FAIL. The 22-op
// RK4F core is the algebraic floor. Remaining fat was handoff: 1.0 -> 0.25
// slots/tstep via stride-8 (consumers recompute 7 intermediate steps,
// bit-identical op order -> outputs bit-identical to R18).
//
// State (sigma, I), sigma = c*S. D from RK4-preserved invariant:
// D = fma(-kD/c, sigma, fma(-kD, I, kD*N)).

#define N_POP 1.0e7f
#define T_PTS 2048
#define KSEG 32                  // handoff slots per segment
#define STRIDE 8                 // tsteps per handoff slot
#define SEG_T (KSEG * STRIDE)    // 256 tsteps per segment
#define NSEG (T_PTS / SEG_T)     // 8 segments

#define LOAD_ACQ(p)  __hip_atomic_load((p), __ATOMIC_ACQUIRE, __HIP_MEMORY_SCOPE_WORKGROUP)
#define STORE_REL(p, v) __hip_atomic_store((p), (v), __ATOMIC_RELEASE, __HIP_MEMORY_SCOPE_WORKGROUP)
#define STORE_RLX(p, v) __hip_atomic_store((p), (v), __ATOMIC_RELAXED, __HIP_MEMORY_SCOPE_WORKGROUP)

// One RK4 step (h=1), 22 ops, 9-op dependent cycle. Updates SG, IV in place.
#define RK4F(SG, IV)                                                         \
    do {                                                                     \
        const float pre1 = __builtin_fmaf(nh2gm, (IV), (IV));                \
        const float m1   = (SG) * (IV);                          /* c1 */    \
        const float s2   = __builtin_fmaf(nch2, m1, (SG));                   \
        const float i2   = __builtin_fmaf(h2, m1, pre1);         /* c2 */    \
        const float pre2 = __builtin_fmaf(nh2gm, i2, (IV));                  \
        const float sip1 = __builtin_fmaf(2.0f, i2, (IV));                   \
        const float m2   = s2 * i2;                              /* c3 */    \
        const float s3   = __builtin_fmaf(nch2, m2, (SG));                   \
        const float smp1 = __builtin_fmaf(2.0f, m2, m1);                     \
        const float i3   = __builtin_fmaf(h2, m2, pre2);         /* c4 */    \
        const float pre3 = __builtin_fmaf(ngm, i3, (IV));                    \
        const float sip2 = __builtin_fmaf(2.0f, i3, sip1);                   \
        const float m3   = s3 * i3;                              /* c5 */    \
        const float s4   = __builtin_fmaf(nch, m3, (SG));                    \
        const float smp2 = __builtin_fmaf(2.0f, m3, smp1);                   \
        const float i4   = m3 + pre3;                            /* c6 */    \
        const float si   = sip2 + i4;                                        \
        const float a    = __builtin_fmaf(nwgm, si, (IV));                   \
        const float m4   = s4 * i4;                              /* c7 */    \
        const float sm   = smp2 + m4;                            /* c8 */    \
        (SG) = __builtin_fmaf(nwc, sm, (SG));                    /* c9a */   \
        (IV) = __builtin_fmaf(w, sm, a);                         /* c9b */   \
    } while (0)

#define INV(SG, IV) __builtin_fmaf(nkc, (SG), __builtin_fmaf(nk, (IV), kDN))

// Emit one float4 = (I_even, D_even, I_odd, D_odd); advances state by 1 step.
#define EMIT_PAIR(IDX)                                                       \
    do {                                                                     \
        const float i0_ = Iv;                                                \
        const float D0_ = INV(sgv, Iv);                                      \
        RK4F(sgv, Iv);                                                       \
        const float D1_ = INV(sgv, Iv);                                      \
        o[IDX] = make_float4(i0_, D0_, Iv, D1_);                             \
    } while (0)

__global__ __launch_bounds__(256, 1) void sird_kernel(const float* __restrict__ alpha,
                                                      float* __restrict__ out) {
    const int lane = threadIdx.x & 63;
    const int wave = threadIdx.x >> 6;        // 0 = producer, 1..3 = consumers
    const int s = blockIdx.x * 64 + lane;     // scenario (same for all waves)

    // SoA, double-buffered: [buf][var][slot][lane], var 0=sigma 1=I. 32 KiB.
    __shared__ float buf[2][2][KSEG][64];
    __shared__ int prod_flag[2];              // last seg written into buffer b
    __shared__ int cons_flag[2][3];           // last seg consumed, per wave

    if (threadIdx.x == 0) {
        prod_flag[0] = prod_flag[1] = -1;
        cons_flag[0][0] = cons_flag[0][1] = cons_flag[0][2] = -1;
        cons_flag[1][0] = cons_flag[1][1] = cons_flag[1][2] = -1;
    }
    __syncthreads();                          // once, before any global store

    const float beta  = alpha[s * 3 + 0];
    const float gamma = alpha[s * 3 + 1];
    const float mu    = alpha[s * 3 + 2];

    const float c     = beta * (1.0f / N_POP);
    const float gm    = gamma + mu;
    const float ngm   = -gm;
    const float h2    = 0.5f;                 // h/2, h = 1
    const float nch2  = -0.5f * c;            // -c*h/2
    const float nch   = -c;                   // -c*h
    const float nh2gm = -0.5f * gm;           // -gm*h/2
    const float w     = 1.0f / 6.0f;
    const float nwc   = -c * (1.0f / 6.0f);
    const float nwgm  = -gm * (1.0f / 6.0f);
    const float kD    = mu / gm;              // gamma,mu > 0 a.s.
    const float kDN   = kD * (float)N_POP;
    const float nkc   = -kD / c;
    const float nk    = -kD;

    float sg = c * (N_POP - 1.0f);            // sigma = c*S
    float I  = 1.0f;

    float2* __restrict__ orow = (float2*)out + (size_t)s * T_PTS;

    if (wave == 0) {
        // ------------------------------ producer ------------------------------
        for (int seg = 0; seg < NSEG; ++seg) {
            const int b = seg & 1;
            if (seg >= 2) {
                while (LOAD_ACQ(&cons_flag[b][0]) < seg - 2 ||
                       LOAD_ACQ(&cons_flag[b][1]) < seg - 2 ||
                       LOAD_ACQ(&cons_flag[b][2]) < seg - 2) { /* spin */ }
            }
            float* bsg = &buf[b][0][0][lane];
            float* bI  = &buf[b][1][0][lane];
#pragma unroll 8
            for (int k = 0; k < KSEG; ++k) {
                bsg[k * 64] = sg;              // ds_write_b32, immediate offset
                bI [k * 64] = I;
                RK4F(sg, I);                   // 8 steps per handoff slot
                RK4F(sg, I);
                RK4F(sg, I);
                RK4F(sg, I);
                RK4F(sg, I);
                RK4F(sg, I);
                RK4F(sg, I);
                RK4F(sg, I);
            }
            if (lane == 0) STORE_REL(&prod_flag[b], seg);  // lgkmcnt drain only
        }
    } else {
        // ------------------------------ consumers -----------------------------
        const int wv = wave - 1;              // 0..2
        for (int seg = 0; seg < NSEG; ++seg) {
            const int b = seg & 1;
            while (LOAD_ACQ(&prod_flag[b]) < seg) { /* spin */ }
            const float* qsg = &buf[b][0][0][lane];
            const float* qI  = &buf[b][1][0][lane];
            float4* op4 = (float4*)(orow + (size_t)seg * SEG_T);
            for (int k = wv; k < KSEG; k += 3) {
                float sgv = qsg[k * 64];
                float Iv  = qI [k * 64];
                float4* o = op4 + k * 4;       // 8 (I,D) pairs = 4 float4
                EMIT_PAIR(0);                  // t+0, t+1   (1 step inside)
                RK4F(sgv, Iv);                 // -> t+2
                EMIT_PAIR(1);                  // t+2, t+3
                RK4F(sgv, Iv);                 // -> t+4
                EMIT_PAIR(2);                  // t+4, t+5
                RK4F(sgv, Iv);                 // -> t+6
                EMIT_PAIR(3);                  // t+6, t+7   (7 steps total)
            }
            // ds_read data already in registers -> relaxed; never drains vmcnt.
            if (lane == 0) STORE_RLX(&cons_flag[b][wv], seg);
        }
    }
}

extern "C" void kernel_launch(void* const* d_in, const int* in_sizes, int n_in,
                              void* d_out, int out_size, void* d_ws, size_t ws_size,
                              hipStream_t stream) {
    const float* alpha = (const float*)d_in[0];
    float* out = (float*)d_out;
    sird_kernel<<<dim3(T_PTS / 64), dim3(256), 0, stream>>>(alpha, out);
}

// Round 7
// 143.284 us; speedup vs baseline: 1.0459x; 1.0459x over previous
//
#include <hip/hip_runtime.h>

// SIRD RK4, round 20: slot-granular ring handoff (stride 16, ring 16) —
// kill R19's 3.9 us last-segment tail and the segment flag machinery.
//
// Machine model (fits R13/R16/R18/R19 within 1%): producer wave is pure
// ISSUE-bound at ~4.71 cyc/slot; dependency-chain length never binds
// (12-chain == 9-chain). Only slot count matters. 22-op RK4F core is the
// algebraic floor; RK3 / h=2 fail the error budget (arithmetic in R19
// header). Remaining fat was (a) R19's coarse-segment tail: last 256-tstep
// segment consumed AFTER producer finishes (~3.9 us), (b) segment flags.
//
// Ring protocol:
//   producer iter k (16 tsteps): [every 4th k: guard min(cons_ctr) >= k-12
//   so slot k&15 is free] -> STORE_REL(prod_ctr=k) (covers slots < k; its
//   lgkmcnt(0) release waits on ds_writes ~350 insts old = zero stall) ->
//   ds_write slot k&15 -> 16x RK4F.
//   consumer wave wv takes k = wv mod 3: spin prod_ctr > k, ds_read slot,
//   recompute 15 intermediate steps (same macro = identical values), emit
//   8x float4 (I,D,I,D), fire-and-forget; cons_ctr[wv] = k+3 (relaxed).
// Consumers have ~2.8x slack -> producer never waits; tail = one slot's
// consume ~0.8 us.
//
// State (sigma, I), sigma = c*S. D from RK4-preserved invariant:
// D = fma(-kD/c, sigma, fma(-kD, I, kD*N)).

#define N_POP 1.0e7f
#define T_PTS 2048
#define STRIDE 16                // tsteps per handoff slot
#define NK (T_PTS / STRIDE)      // 128 producer iters
#define RING 16                  // ring slots (8 KiB state)

#define LOAD_ACQ(p)  __hip_atomic_load((p), __ATOMIC_ACQUIRE, __HIP_MEMORY_SCOPE_WORKGROUP)
#define STORE_REL(p, v) __hip_atomic_store((p), (v), __ATOMIC_RELEASE, __HIP_MEMORY_SCOPE_WORKGROUP)
#define STORE_RLX(p, v) __hip_atomic_store((p), (v), __ATOMIC_RELAXED, __HIP_MEMORY_SCOPE_WORKGROUP)

// One RK4 step (h=1), 22 ops, 9-op dependent cycle. Updates SG, IV in place.
#define RK4F(SG, IV)                                                         \
    do {                                                                     \
        const float pre1 = __builtin_fmaf(nh2gm, (IV), (IV));                \
        const float m1   = (SG) * (IV);                          /* c1 */    \
        const float s2   = __builtin_fmaf(nch2, m1, (SG));                   \
        const float i2   = __builtin_fmaf(h2, m1, pre1);         /* c2 */    \
        const float pre2 = __builtin_fmaf(nh2gm, i2, (IV));                  \
        const float sip1 = __builtin_fmaf(2.0f, i2, (IV));                   \
        const float m2   = s2 * i2;                              /* c3 */    \
        const float s3   = __builtin_fmaf(nch2, m2, (SG));                   \
        const float smp1 = __builtin_fmaf(2.0f, m2, m1);                     \
        const float i3   = __builtin_fmaf(h2, m2, pre2);         /* c4 */    \
        const float pre3 = __builtin_fmaf(ngm, i3, (IV));                    \
        const float sip2 = __builtin_fmaf(2.0f, i3, sip1);                   \
        const float m3   = s3 * i3;                              /* c5 */    \
        const float s4   = __builtin_fmaf(nch, m3, (SG));                    \
        const float smp2 = __builtin_fmaf(2.0f, m3, smp1);                   \
        const float i4   = m3 + pre3;                            /* c6 */    \
        const float si   = sip2 + i4;                                        \
        const float a    = __builtin_fmaf(nwgm, si, (IV));                   \
        const float m4   = s4 * i4;                              /* c7 */    \
        const float sm   = smp2 + m4;                            /* c8 */    \
        (SG) = __builtin_fmaf(nwc, sm, (SG));                    /* c9a */   \
        (IV) = __builtin_fmaf(w, sm, a);                         /* c9b */   \
    } while (0)

#define INV(SG, IV) __builtin_fmaf(nkc, (SG), __builtin_fmaf(nk, (IV), kDN))

// Emit one float4 = (I_even, D_even, I_odd, D_odd); advances state by 1 step.
#define EMIT_PAIR(IDX)                                                       \
    do {                                                                     \
        const float i0_ = Iv;                                                \
        const float D0_ = INV(sgv, Iv);                                      \
        RK4F(sgv, Iv);                                                       \
        const float D1_ = INV(sgv, Iv);                                      \
        o[IDX] = make_float4(i0_, D0_, Iv, D1_);                             \
    } while (0)

__global__ __launch_bounds__(256, 1) void sird_kernel(const float* __restrict__ alpha,
                                                      float* __restrict__ out) {
    const int lane = threadIdx.x & 63;
    const int wave = threadIdx.x >> 6;        // 0 = producer, 1..3 = consumers
    const int s = blockIdx.x * 64 + lane;     // scenario (same for all waves)

    // Ring of handoff states, SoA: [var][slot][lane], var 0=sigma 1=I. 8 KiB.
    __shared__ float buf[2][RING][64];
    __shared__ int prod_ctr;                  // slots < prod_ctr are ready
    __shared__ int cons_ctr[3];               // wave wv done with assigned < ctr

    if (threadIdx.x == 0) {
        prod_ctr = 0;
        cons_ctr[0] = 0; cons_ctr[1] = 1; cons_ctr[2] = 2;
    }
    __syncthreads();                          // once, before any handoff

    const float beta  = alpha[s * 3 + 0];
    const float gamma = alpha[s * 3 + 1];
    const float mu    = alpha[s * 3 + 2];

    const float c     = beta * (1.0f / N_POP);
    const float gm    = gamma + mu;
    const float ngm   = -gm;
    const float h2    = 0.5f;                 // h/2, h = 1
    const float nch2  = -0.5f * c;            // -c*h/2
    const float nch   = -c;                   // -c*h
    const float nh2gm = -0.5f * gm;           // -gm*h/2
    const float w     = 1.0f / 6.0f;
    const float nwc   = -c * (1.0f / 6.0f);
    const float nwgm  = -gm * (1.0f / 6.0f);
    const float kD    = mu / gm;              // gamma,mu > 0 a.s.
    const float kDN   = kD * (float)N_POP;
    const float nkc   = -kD / c;
    const float nk    = -kD;

    float2* __restrict__ orow = (float2*)out + (size_t)s * T_PTS;

    if (wave == 0) {
        // ------------------------------ producer ------------------------------
        float sg = c * (N_POP - 1.0f);        // sigma = c*S
        float I  = 1.0f;
        float* bsg = &buf[0][0][lane];
        float* bI  = &buf[1][0][lane];
#pragma unroll 4
        for (int k = 0; k < NK; ++k) {
            if ((k & 3) == 0 && k >= RING) {
                // Slots k..k+3 (mod RING) reused; consumers must have finished
                // assigned iters <= k+3-RING  ->  all cons_ctr >= k-12.
                while (LOAD_ACQ(&cons_ctr[0]) < k - (RING - 4) ||
                       LOAD_ACQ(&cons_ctr[1]) < k - (RING - 4) ||
                       LOAD_ACQ(&cons_ctr[2]) < k - (RING - 4)) { /* spin */ }
            }
            if (lane == 0) STORE_REL(&prod_ctr, k);   // slots < k ready
            const int sl = (k & (RING - 1)) * 64;
            bsg[sl] = sg;                      // ds_write_b32, SoA
            bI [sl] = I;
            RK4F(sg, I);  RK4F(sg, I);  RK4F(sg, I);  RK4F(sg, I);
            RK4F(sg, I);  RK4F(sg, I);  RK4F(sg, I);  RK4F(sg, I);
            RK4F(sg, I);  RK4F(sg, I);  RK4F(sg, I);  RK4F(sg, I);
            RK4F(sg, I);  RK4F(sg, I);  RK4F(sg, I);  RK4F(sg, I);
        }
        if (lane == 0) STORE_REL(&prod_ctr, NK);      // final publish
    } else {
        // ------------------------------ consumers -----------------------------
        const int wv = wave - 1;              // 0..2; takes k % 3 == wv
        const float* qsg = &buf[0][0][lane];
        const float* qI  = &buf[1][0][lane];
        for (int k = wv; k < NK; k += 3) {
            while (LOAD_ACQ(&prod_ctr) <= k) { /* spin */ }
            const int sl = (k & (RING - 1)) * 64;
            float sgv = qsg[sl];
            float Iv  = qI [sl];
            float4* o = (float4*)(orow + (size_t)k * STRIDE);  // 8 float4
            EMIT_PAIR(0);  RK4F(sgv, Iv);      // t+0..1, -> t+2
            EMIT_PAIR(1);  RK4F(sgv, Iv);      // t+2..3, -> t+4
            EMIT_PAIR(2);  RK4F(sgv, Iv);      // t+4..5, -> t+6
            EMIT_PAIR(3);  RK4F(sgv, Iv);      // t+6..7, -> t+8
            EMIT_PAIR(4);  RK4F(sgv, Iv);      // t+8..9, -> t+10
            EMIT_PAIR(5);  RK4F(sgv, Iv);      // t+10..11, -> t+12
            EMIT_PAIR(6);  RK4F(sgv, Iv);      // t+12..13, -> t+14
            EMIT_PAIR(7);                      // t+14..15 (15 RK4F total)
            // ds_reads already landed in regs (in-order DS pipe); never
            // drains vmcnt -> stores stay fire-and-forget.
            if (lane == 0) STORE_RLX(&cons_ctr[wv], k + 3);
        }
    }
}

extern "C" void kernel_launch(void* const* d_in, const int* in_sizes, int n_in,
                              void* d_out, int out_size, void* d_ws, size_t ws_size,
                              hipStream_t stream) {
    const float* alpha = (const float*)d_in[0];
    float* out = (float*)d_out;
    sird_kernel<<<dim3(T_PTS / 64), dim3(256), 0, stream>>>(alpha, out);
}